// Round 1
// baseline (701.638 us; speedup 1.0000x reference)
//
#include <hip/hip_runtime.h>
#include <math.h>

typedef unsigned short u16;
typedef short short8 __attribute__((ext_vector_type(8)));
typedef float f32x4 __attribute__((ext_vector_type(4)));

#define TT 4
#define BB 4096
#define DIM 512
#define HDIM 1024
#define BD (BB*DIM)      // 2097152
#define BH (BB*HDIM)     // 4194304
#define D2 (DIM*DIM)     // 262144
#define NEXP 20

#define GLOAD16(gp, lp) __builtin_amdgcn_global_load_lds( \
    (__attribute__((address_space(1))) void*)(void*)(gp), \
    (__attribute__((address_space(3))) void*)(void*)(lp), 16, 0, 0)

__device__ __forceinline__ u16 f2b(float f) {
  union { float f; unsigned u; } x; x.f = f;
  unsigned r = x.u + 0x7FFFu + ((x.u >> 16) & 1u);
  return (u16)(r >> 16);
}

__device__ __forceinline__ float wsum(float v) {
#pragma unroll
  for (int o = 32; o > 0; o >>= 1) v += __shfl_xor(v, o);
  return v;
}

// ---------------- prep: x_s = mean_t(x), bf16 casts of inputs ----------------
__global__ __launch_bounds__(256) void k_prep(const float* __restrict__ ti,
                                              u16* __restrict__ tib,
                                              u16* __restrict__ xsb,
                                              float* __restrict__ xsf) {
  size_t i = ((size_t)blockIdx.x * 256 + threadIdx.x) * 4;
  float4 v0 = *(const float4*)(ti + i);
  float4 v1 = *(const float4*)(ti + (size_t)BD + i);
  float4 v2 = *(const float4*)(ti + 2 * (size_t)BD + i);
  float4 v3 = *(const float4*)(ti + 3 * (size_t)BD + i);
  ushort4 c0 = { f2b(v0.x), f2b(v0.y), f2b(v0.z), f2b(v0.w) };
  ushort4 c1 = { f2b(v1.x), f2b(v1.y), f2b(v1.z), f2b(v1.w) };
  ushort4 c2 = { f2b(v2.x), f2b(v2.y), f2b(v2.z), f2b(v2.w) };
  ushort4 c3 = { f2b(v3.x), f2b(v3.y), f2b(v3.z), f2b(v3.w) };
  *(ushort4*)(tib + i) = c0;
  *(ushort4*)(tib + (size_t)BD + i) = c1;
  *(ushort4*)(tib + 2 * (size_t)BD + i) = c2;
  *(ushort4*)(tib + 3 * (size_t)BD + i) = c3;
  float4 m;
  m.x = (v0.x + v1.x + v2.x + v3.x) * 0.25f;
  m.y = (v0.y + v1.y + v2.y + v3.y) * 0.25f;
  m.z = (v0.z + v1.z + v2.z + v3.z) * 0.25f;
  m.w = (v0.w + v1.w + v2.w + v3.w) * 0.25f;
  *(float4*)(xsf + i) = m;
  ushort4 mb = { f2b(m.x), f2b(m.y), f2b(m.z), f2b(m.w) };
  *(ushort4*)(xsb + i) = mb;
}

// ------------- batched transpose+cast: (G,R,C) f32 -> (G,C,R) bf16 -----------
__global__ __launch_bounds__(256) void k_tcast(const float* __restrict__ in,
                                               u16* __restrict__ out,
                                               int R, int C) {
  __shared__ float tile[32][33];
  size_t gb = (size_t)blockIdx.z * R * C;
  in += gb; out += gb;
  int c0 = blockIdx.x * 32, r0 = blockIdx.y * 32;
  int tx = threadIdx.x & 31, ty = threadIdx.x >> 5;
#pragma unroll
  for (int j = 0; j < 4; j++)
    tile[ty + j * 8][tx] = in[(size_t)(r0 + ty + j * 8) * C + c0 + tx];
  __syncthreads();
#pragma unroll
  for (int j = 0; j < 4; j++)
    out[(size_t)(c0 + ty + j * 8) * R + r0 + tx] = f2b(tile[tx][ty + j * 8]);
}

// ---------------- plain cast f32 -> bf16 -------------------------------------
__global__ __launch_bounds__(256) void k_cast(const float* __restrict__ in,
                                              u16* __restrict__ out) {
  size_t i = ((size_t)blockIdx.x * 256 + threadIdx.x) * 4;
  float4 v = *(const float4*)(in + i);
  ushort4 b = { f2b(v.x), f2b(v.y), f2b(v.z), f2b(v.w) };
  *(ushort4*)(out + i) = b;
}

// --------------- small bias-vector precomputes (all zero in practice) --------
// qwkb[t,c] = sum_e qw[t,c,e]*kb[t,e];  kwqb[t,d] = sum_e kw[t,d,e]*qb[t,e];
// kbqb[t] = kb[t].qb[t]
__global__ __launch_bounds__(256) void k_biasvec(const float* __restrict__ qw,
                                                 const float* __restrict__ kb,
                                                 const float* __restrict__ kw,
                                                 const float* __restrict__ qb,
                                                 float* __restrict__ qwkb,
                                                 float* __restrict__ kwqb,
                                                 float* __restrict__ kbqb) {
  int gw = (blockIdx.x * 256 + threadIdx.x) >> 6;
  int lane = threadIdx.x & 63;
  if (gw < 2048) {
    int t = gw >> 9, c = gw & 511;
    const float* row = qw + ((size_t)t * DIM + c) * DIM;
    const float* v = kb + (size_t)t * DIM;
    float s = 0;
#pragma unroll
    for (int j = 0; j < 8; j++) s += row[lane * 8 + j] * v[lane * 8 + j];
    s = wsum(s);
    if (lane == 0) qwkb[(size_t)t * DIM + c] = s;
  } else if (gw < 4096) {
    int t = (gw - 2048) >> 9, d = gw & 511;
    const float* row = kw + ((size_t)t * DIM + d) * DIM;
    const float* v = qb + (size_t)t * DIM;
    float s = 0;
#pragma unroll
    for (int j = 0; j < 8; j++) s += row[lane * 8 + j] * v[lane * 8 + j];
    s = wsum(s);
    if (lane == 0) kwqb[(size_t)t * DIM + d] = s;
  } else if (gw < 4100) {
    int t = gw - 4096;
    const float* a = kb + (size_t)t * DIM;
    const float* c = qb + (size_t)t * DIM;
    float s = 0;
#pragma unroll
    for (int j = 0; j < 8; j++) s += a[lane * 8 + j] * c[lane * 8 + j];
    s = wsum(s);
    if (lane == 0) kbqb[t] = s;
  }
}

// ---------------- 128x128 bf16 MFMA GEMM mainloop (NT: A MxK, B NxK) ---------
__device__ __forceinline__ void gemm128(const u16* __restrict__ Ag, int lda,
                                        const u16* __restrict__ Bg, int ldb,
                                        int K, f32x4 acc[4][4]) {
  __shared__ u16 lA[4096];
  __shared__ u16 lB[4096];
  const int tid = threadIdx.x;
  const int lane = tid & 63;
  const int wave = tid >> 6;
  const int wm = wave >> 1, wn = wave & 1;
  const u16* a0 = Ag + (size_t)(tid >> 2) * lda + (tid & 3) * 8;
  const u16* a1 = a0 + (size_t)64 * lda;
  const u16* b0 = Bg + (size_t)(tid >> 2) * ldb + (tid & 3) * 8;
  const u16* b1 = b0 + (size_t)64 * ldb;
  u16* la0 = &lA[tid * 8];
  u16* la1 = &lA[2048 + tid * 8];
  u16* lb0 = &lB[tid * 8];
  u16* lb1 = &lB[2048 + tid * 8];
  const int ao = (wm * 64 + (lane & 15)) * 32 + (lane >> 4) * 8;
  const int bo = (wn * 64 + (lane & 15)) * 32 + (lane >> 4) * 8;
  for (int k0 = 0; k0 < K; k0 += 32) {
    __syncthreads();                    // previous tile fully consumed
    GLOAD16(a0 + k0, la0);
    GLOAD16(a1 + k0, la1);
    GLOAD16(b0 + k0, lb0);
    GLOAD16(b1 + k0, lb1);
    __syncthreads();                    // staging complete (vmcnt(0) drained)
    short8 af[4], bf[4];
#pragma unroll
    for (int i = 0; i < 4; i++) {
      af[i] = *(const short8*)&lA[ao + i * 512];
      bf[i] = *(const short8*)&lB[bo + i * 512];
    }
#pragma unroll
    for (int mi = 0; mi < 4; mi++)
#pragma unroll
      for (int ni = 0; ni < 4; ni++)
        acc[mi][ni] = __builtin_amdgcn_mfma_f32_16x16x32_bf16(af[mi], bf[ni],
                                                              acc[mi][ni], 0, 0, 0);
  }
}

// ---------------- expert up-GEMM: h = gelu(x@W1 + b1), bf16 out --------------
__global__ __launch_bounds__(256) void k_gemm_up(const u16* __restrict__ xsb,
                                                 const u16* __restrict__ tib,
                                                 const u16* __restrict__ w1t,
                                                 const float* __restrict__ sb1,
                                                 const float* __restrict__ tb1,
                                                 u16* __restrict__ hbuf,
                                                 int expertBase) {
  int gz = blockIdx.z, ge = expertBase + gz;
  const u16* A;
  const float* bias;
  if (ge < 4) { A = xsb; bias = sb1 + (size_t)ge * HDIM; }
  else {
    int te = ge - 4;
    A = tib + (size_t)(te >> 2) * BD;
    bias = tb1 + (size_t)te * HDIM;
  }
  const u16* W = w1t + (size_t)ge * ((size_t)HDIM * DIM);
  int m0 = blockIdx.y * 128, n0 = blockIdx.x * 128;
  f32x4 acc[4][4] = {};
  gemm128(A + (size_t)m0 * DIM, DIM, W + (size_t)n0 * DIM, DIM, DIM, acc);
  u16* out = hbuf + (size_t)gz * BH;
  const int lane = threadIdx.x & 63, wave = threadIdx.x >> 6;
  const int rbase = m0 + (wave >> 1) * 64 + (lane >> 4) * 4;
  const int cbase = n0 + (wave & 1) * 64 + (lane & 15);
#pragma unroll
  for (int mi = 0; mi < 4; mi++)
#pragma unroll
    for (int ni = 0; ni < 4; ni++)
#pragma unroll
      for (int r = 0; r < 4; r++) {
        int row = rbase + mi * 16 + r;
        int col = cbase + ni * 16;
        float v = acc[mi][ni][r] + bias[col];
        v = 0.5f * v * (1.0f + erff(v * 0.70710678118654752f));
        out[(size_t)row * HDIM + col] = f2b(v);
      }
}

// ------- expert down-GEMM: preLN = h@W2 + b2 + residual -> stacked slots -----
__global__ __launch_bounds__(256) void k_gemm_down(const u16* __restrict__ hbuf,
                                                   const u16* __restrict__ w2t,
                                                   const float* __restrict__ sb2,
                                                   const float* __restrict__ tb2,
                                                   const float* __restrict__ xsf,
                                                   const float* __restrict__ tif,
                                                   float* __restrict__ stacked,
                                                   int expertBase) {
  int gz = blockIdx.z, ge = expertBase + gz;
  const u16* A = hbuf + (size_t)gz * BH;
  const u16* W = w2t + (size_t)ge * ((size_t)DIM * HDIM);
  int m0 = blockIdx.y * 128, n0 = blockIdx.x * 128;
  f32x4 acc[4][4] = {};
  gemm128(A + (size_t)m0 * HDIM, HDIM, W + (size_t)n0 * HDIM, HDIM, HDIM, acc);
  const float* bias;
  const float* res;
  int te = ge - 4;
  if (ge < 4) { bias = sb2 + (size_t)ge * DIM; res = xsf; }
  else { bias = tb2 + (size_t)te * DIM; res = tif + (size_t)(te >> 2) * BD; }
  const int lane = threadIdx.x & 63, wave = threadIdx.x >> 6;
  const int rbase = m0 + (wave >> 1) * 64 + (lane >> 4) * 4;
  const int cbase = n0 + (wave & 1) * 64 + (lane & 15);
#pragma unroll
  for (int mi = 0; mi < 4; mi++)
#pragma unroll
    for (int ni = 0; ni < 4; ni++)
#pragma unroll
      for (int r = 0; r < 4; r++) {
        int row = rbase + mi * 16 + r;
        int col = cbase + ni * 16;
        float v = acc[mi][ni][r] + bias[col] + res[(size_t)row * DIM + col];
        if (ge < 4) {
#pragma unroll
          for (int t = 0; t < 4; t++)
            stacked[(((size_t)t * 8 + ge) * BB + row) * DIM + col] = v;
        } else {
          int t = te >> 2, n = 4 + (te & 3);
          stacked[(((size_t)t * 8 + n) * BB + row) * DIM + col] = v;
        }
      }
}

// ---------------- MT[t] = kw[t] @ qw[t]^T  (bf16 out) ------------------------
__global__ __launch_bounds__(256) void k_gemm_mt(const u16* __restrict__ kwb,
                                                 const u16* __restrict__ qwb,
                                                 u16* __restrict__ mt) {
  int t = blockIdx.z;
  int m0 = blockIdx.y * 128, n0 = blockIdx.x * 128;
  f32x4 acc[4][4] = {};
  gemm128(kwb + (size_t)t * D2 + (size_t)m0 * DIM, DIM,
          qwb + (size_t)t * D2 + (size_t)n0 * DIM, DIM, DIM, acc);
  const int lane = threadIdx.x & 63, wave = threadIdx.x >> 6;
  const int rbase = m0 + (wave >> 1) * 64 + (lane >> 4) * 4;
  const int cbase = n0 + (wave & 1) * 64 + (lane & 15);
#pragma unroll
  for (int mi = 0; mi < 4; mi++)
#pragma unroll
    for (int ni = 0; ni < 4; ni++)
#pragma unroll
      for (int r = 0; r < 4; r++)
        mt[(size_t)t * D2 + (size_t)(rbase + mi * 16 + r) * DIM + cbase + ni * 16] =
            f2b(acc[mi][ni][r]);
}

// ---------------- qk[t] = x[t] @ MT[t]^T + kwqb[t]  (f32 out) ----------------
__global__ __launch_bounds__(256) void k_gemm_qk(const u16* __restrict__ tib,
                                                 const u16* __restrict__ mt,
                                                 const float* __restrict__ kwqb,
                                                 float* __restrict__ qk) {
  int t = blockIdx.z;
  int m0 = blockIdx.y * 128, n0 = blockIdx.x * 128;
  f32x4 acc[4][4] = {};
  gemm128(tib + (size_t)t * BD + (size_t)m0 * DIM, DIM,
          mt + (size_t)t * D2 + (size_t)n0 * DIM, DIM, DIM, acc);
  const int lane = threadIdx.x & 63, wave = threadIdx.x >> 6;
  const int rbase = m0 + (wave >> 1) * 64 + (lane >> 4) * 4;
  const int cbase = n0 + (wave & 1) * 64 + (lane & 15);
#pragma unroll
  for (int mi = 0; mi < 4; mi++)
#pragma unroll
    for (int ni = 0; ni < 4; ni++)
#pragma unroll
      for (int r = 0; r < 4; r++) {
        int col = cbase + ni * 16;
        qk[(size_t)t * BD + (size_t)(rbase + mi * 16 + r) * DIM + col] =
            acc[mi][ni][r] + kwqb[(size_t)t * DIM + col];
      }
}

// ---------------- in-place layernorm over stacked ----------------------------
__global__ __launch_bounds__(256) void k_ln(float* __restrict__ stk,
                                            const float* __restrict__ sg,
                                            const float* __restrict__ sbt,
                                            const float* __restrict__ tg,
                                            const float* __restrict__ tbt) {
  int gw = (blockIdx.x * 256 + threadIdx.x) >> 6;
  int lane = threadIdx.x & 63;
  int b = gw & (BB - 1);
  int tn = gw >> 12, n = tn & 7, t = tn >> 3;
  float* row = stk + ((size_t)tn * BB + b) * DIM + lane * 8;
  float x[8];
  *(float4*)&x[0] = *(const float4*)(row);
  *(float4*)&x[4] = *(const float4*)(row + 4);
  float s = 0, q = 0;
#pragma unroll
  for (int j = 0; j < 8; j++) { s += x[j]; q += x[j] * x[j]; }
  s = wsum(s); q = wsum(q);
  float mu = s * (1.0f / DIM);
  float var = q * (1.0f / DIM) - mu * mu;
  float rs = rsqrtf(var + 1e-5f);
  const float* gp;
  const float* bp;
  if (n < 4) { gp = sg + (size_t)n * DIM; bp = sbt + (size_t)n * DIM; }
  else {
    int te = t * 4 + (n - 4);
    gp = tg + (size_t)te * DIM;
    bp = tbt + (size_t)te * DIM;
  }
  float gv[8], bv[8];
  *(float4*)&gv[0] = *(const float4*)(gp + lane * 8);
  *(float4*)&gv[4] = *(const float4*)(gp + lane * 8 + 4);
  *(float4*)&bv[0] = *(const float4*)(bp + lane * 8);
  *(float4*)&bv[4] = *(const float4*)(bp + lane * 8 + 4);
  float y[8];
#pragma unroll
  for (int j = 0; j < 8; j++) y[j] = (x[j] - mu) * rs * gv[j] + bv[j];
  *(float4*)(row) = *(float4*)&y[0];
  *(float4*)(row + 4) = *(float4*)&y[4];
}

// ------------ fused scores + softmax + gating (one wave per (t,b)) -----------
__global__ __launch_bounds__(256) void k_score(const float* __restrict__ stk,
                                               const float* __restrict__ qk,
                                               const float* __restrict__ xin,
                                               const float* __restrict__ qwkb,
                                               const float* __restrict__ kbqb,
                                               float* __restrict__ gated,
                                               float* __restrict__ wout) {
  int gw = (blockIdx.x * 256 + threadIdx.x) >> 6;
  int lane = threadIdx.x & 63;
  int b = gw & (BB - 1), t = gw >> 12;
  int d0 = lane * 8;
  size_t rowoff = ((size_t)t * BB + b) * DIM + d0;
  float qr[8], xr[8], wk[8];
  *(float4*)&qr[0] = *(const float4*)(qk + rowoff);
  *(float4*)&qr[4] = *(const float4*)(qk + rowoff + 4);
  *(float4*)&xr[0] = *(const float4*)(xin + rowoff);
  *(float4*)&xr[4] = *(const float4*)(xin + rowoff + 4);
  *(float4*)&wk[0] = *(const float4*)(qwkb + (size_t)t * DIM + d0);
  *(float4*)&wk[4] = *(const float4*)(qwkb + (size_t)t * DIM + d0 + 4);
  float stv[8][8];
  float dots[8];
#pragma unroll
  for (int n = 0; n < 8; n++) {
    const float* sr = stk + (((size_t)t * 8 + n) * BB + b) * DIM + d0;
    *(float4*)&stv[n][0] = *(const float4*)(sr);
    *(float4*)&stv[n][4] = *(const float4*)(sr + 4);
    float s = 0;
#pragma unroll
    for (int j = 0; j < 8; j++) s += stv[n][j] * qr[j];
    dots[n] = wsum(s);
  }
  float sbp = 0;
#pragma unroll
  for (int j = 0; j < 8; j++) sbp += xr[j] * wk[j];
  float sb = wsum(sbp) + kbqb[t];
  const float inv = 0.04419417382415922f;  // 1/sqrt(512)
  float sc[8], e[8];
  float mx = -1e30f;
#pragma unroll
  for (int n = 0; n < 8; n++) { sc[n] = (dots[n] + sb) * inv; mx = fmaxf(mx, sc[n]); }
  float den = 0;
#pragma unroll
  for (int n = 0; n < 8; n++) { e[n] = expf(sc[n] - mx); den += e[n]; }
  float rden = 1.0f / den;
  float wv[8];
#pragma unroll
  for (int n = 0; n < 8; n++) wv[n] = e[n] * rden;
  float wsel = 0;
#pragma unroll
  for (int n = 0; n < 8; n++) wsel = (lane == n) ? wv[n] : wsel;
  if (lane < 8) wout[((size_t)t * BB + b) * 8 + lane] = wsel;
  float g[8];
#pragma unroll
  for (int j = 0; j < 8; j++) {
    float s = 0;
#pragma unroll
    for (int n = 0; n < 8; n++) s += wv[n] * stv[n][j];
    g[j] = s;
  }
  float* go = gated + rowoff;
  *(float4*)(go) = *(float4*)&g[0];
  *(float4*)(go + 4) = *(float4*)&g[4];
}

// ============================ host launcher ==================================
extern "C" void kernel_launch(void* const* d_in, const int* in_sizes, int n_in,
                              void* d_out, int out_size, void* d_ws, size_t ws_size,
                              hipStream_t stream) {
  const float* ti  = (const float*)d_in[0];
  const float* sw1 = (const float*)d_in[1];
  const float* sb1 = (const float*)d_in[2];
  const float* sw2 = (const float*)d_in[3];
  const float* sb2 = (const float*)d_in[4];
  const float* sg  = (const float*)d_in[5];
  const float* sbt = (const float*)d_in[6];
  const float* tw1 = (const float*)d_in[7];
  const float* tb1 = (const float*)d_in[8];
  const float* tw2 = (const float*)d_in[9];
  const float* tb2 = (const float*)d_in[10];
  const float* tg  = (const float*)d_in[11];
  const float* tbt = (const float*)d_in[12];
  const float* qw  = (const float*)d_in[13];
  const float* qb  = (const float*)d_in[14];
  const float* kw  = (const float*)d_in[15];
  const float* kb  = (const float*)d_in[16];

  float* out = (float*)d_out;
  float* gated   = out;                                   // T*B*D
  float* weights = out + (size_t)TT * BB * DIM;           // T*B*8
  float* stacked = weights + (size_t)TT * BB * 8;         // T*8*B*D

  char* ws = (char*)d_ws;
  u16*   tib  = (u16*)(ws);                     // 16,777,216 B
  u16*   xsb  = (u16*)(ws + 16777216);          //  4,194,304 B
  float* xsf  = (float*)(ws + 20971520);        //  8,388,608 B
  u16*   w1t  = (u16*)(ws + 29360128);          // 20,971,520 B
  u16*   w2t  = (u16*)(ws + 50331648);          // 20,971,520 B
  u16*   qwb  = (u16*)(ws + 71303168);          //  2,097,152 B
  u16*   kwb  = (u16*)(ws + 73400320);          //  2,097,152 B
  u16*   mt   = (u16*)(ws + 75497472);          //  2,097,152 B
  float* qk   = (float*)(ws + 77594624);        // 33,554,432 B
  float* qwkb = (float*)(ws + 111149056);       //      8,192 B
  float* kwqb = (float*)(ws + 111157248);       //      8,192 B
  float* kbqb = (float*)(ws + 111165440);       //        256 B
  u16*   hbuf = (u16*)(ws + 111165696);         // chunk * 8,388,608 B

  const size_t hbase = 111165696;
  int chunk = 20;
  if (ws_size < hbase + (size_t)20 * BH * 2)
    chunk = (ws_size >= hbase + (size_t)4 * BH * 2) ? 4 : 1;

  k_prep<<<2048, 256, 0, stream>>>(ti, tib, xsb, xsf);

  k_tcast<<<dim3(32, 16, 4), 256, 0, stream>>>(sw1, w1t, DIM, HDIM);
  k_tcast<<<dim3(32, 16, 16), 256, 0, stream>>>(tw1, w1t + (size_t)4 * HDIM * DIM, DIM, HDIM);
  k_tcast<<<dim3(16, 32, 4), 256, 0, stream>>>(sw2, w2t, HDIM, DIM);
  k_tcast<<<dim3(16, 32, 16), 256, 0, stream>>>(tw2, w2t + (size_t)4 * DIM * HDIM, HDIM, DIM);
  k_cast<<<1024, 256, 0, stream>>>(qw, qwb);
  k_cast<<<1024, 256, 0, stream>>>(kw, kwb);
  k_biasvec<<<1025, 256, 0, stream>>>(qw, kb, kw, qb, qwkb, kwqb, kbqb);

  k_gemm_mt<<<dim3(4, 4, 4), 256, 0, stream>>>(kwb, qwb, mt);

  for (int base = 0; base < NEXP; base += chunk) {
    int c = NEXP - base < chunk ? NEXP - base : chunk;
    k_gemm_up<<<dim3(8, 32, c), 256, 0, stream>>>(xsb, tib, w1t, sb1, tb1, hbuf, base);
    k_gemm_down<<<dim3(4, 32, c), 256, 0, stream>>>(hbuf, w2t, sb2, tb2, xsf, ti, stacked, base);
  }

  k_gemm_qk<<<dim3(4, 32, 4), 256, 0, stream>>>(tib, mt, kwqb, qk);

  k_ln<<<32768, 256, 0, stream>>>(stacked, sg, sbt, tg, tbt);

  k_score<<<4096, 256, 0, stream>>>(stacked, qk, ti, qwkb, kbqb, gated, weights);
}

// Round 2
// 605.839 us; speedup vs baseline: 1.1581x; 1.1581x over previous
//
#include <hip/hip_runtime.h>
#include <math.h>

typedef unsigned short u16;
typedef short short8 __attribute__((ext_vector_type(8)));
typedef float f32x4 __attribute__((ext_vector_type(4)));

#define TT 4
#define BB 4096
#define DIM 512
#define HDIM 1024
#define BD (BB*DIM)      // 2097152
#define BH (BB*HDIM)     // 4194304
#define D2 (DIM*DIM)     // 262144
#define NEXP 20

#define GLOAD16(gp, lp) __builtin_amdgcn_global_load_lds( \
    (__attribute__((address_space(1))) void*)(void*)(gp), \
    (__attribute__((address_space(3))) void*)(void*)(lp), 16, 0, 0)

__device__ __forceinline__ u16 f2b(float f) {
  union { float f; unsigned u; } x; x.f = f;
  unsigned r = x.u + 0x7FFFu + ((x.u >> 16) & 1u);
  return (u16)(r >> 16);
}

__device__ __forceinline__ float wsum(float v) {
#pragma unroll
  for (int o = 32; o > 0; o >>= 1) v += __shfl_xor(v, o);
  return v;
}

// fast exact-enough GELU: v * sigmoid(1.5957691*v*(1+0.044715 v^2))
__device__ __forceinline__ float fgelu(float v) {
  float u = 1.5957691216057308f * v * (1.0f + 0.044715f * v * v);
  return v / (1.0f + __expf(-u));
}

// ---------------- prep: x_s = mean_t(x), bf16 casts of inputs ----------------
__global__ __launch_bounds__(256) void k_prep(const float* __restrict__ ti,
                                              u16* __restrict__ tib,
                                              u16* __restrict__ xsb,
                                              float* __restrict__ xsf) {
  size_t i = ((size_t)blockIdx.x * 256 + threadIdx.x) * 4;
  float4 v0 = *(const float4*)(ti + i);
  float4 v1 = *(const float4*)(ti + (size_t)BD + i);
  float4 v2 = *(const float4*)(ti + 2 * (size_t)BD + i);
  float4 v3 = *(const float4*)(ti + 3 * (size_t)BD + i);
  ushort4 c0 = { f2b(v0.x), f2b(v0.y), f2b(v0.z), f2b(v0.w) };
  ushort4 c1 = { f2b(v1.x), f2b(v1.y), f2b(v1.z), f2b(v1.w) };
  ushort4 c2 = { f2b(v2.x), f2b(v2.y), f2b(v2.z), f2b(v2.w) };
  ushort4 c3 = { f2b(v3.x), f2b(v3.y), f2b(v3.z), f2b(v3.w) };
  *(ushort4*)(tib + i) = c0;
  *(ushort4*)(tib + (size_t)BD + i) = c1;
  *(ushort4*)(tib + 2 * (size_t)BD + i) = c2;
  *(ushort4*)(tib + 3 * (size_t)BD + i) = c3;
  float4 m;
  m.x = (v0.x + v1.x + v2.x + v3.x) * 0.25f;
  m.y = (v0.y + v1.y + v2.y + v3.y) * 0.25f;
  m.z = (v0.z + v1.z + v2.z + v3.z) * 0.25f;
  m.w = (v0.w + v1.w + v2.w + v3.w) * 0.25f;
  *(float4*)(xsf + i) = m;
  ushort4 mb = { f2b(m.x), f2b(m.y), f2b(m.z), f2b(m.w) };
  *(ushort4*)(xsb + i) = mb;
}

// ------------- batched transpose+cast: (G,R,C) f32 -> (G,C,R) bf16 -----------
__global__ __launch_bounds__(256) void k_tcast(const float* __restrict__ in,
                                               u16* __restrict__ out,
                                               int R, int C) {
  __shared__ float tile[32][33];
  size_t gb = (size_t)blockIdx.z * R * C;
  in += gb; out += gb;
  int c0 = blockIdx.x * 32, r0 = blockIdx.y * 32;
  int tx = threadIdx.x & 31, ty = threadIdx.x >> 5;
#pragma unroll
  for (int j = 0; j < 4; j++)
    tile[ty + j * 8][tx] = in[(size_t)(r0 + ty + j * 8) * C + c0 + tx];
  __syncthreads();
#pragma unroll
  for (int j = 0; j < 4; j++)
    out[(size_t)(c0 + ty + j * 8) * R + r0 + tx] = f2b(tile[tx][ty + j * 8]);
}

// ---------------- plain cast f32 -> bf16 -------------------------------------
__global__ __launch_bounds__(256) void k_cast(const float* __restrict__ in,
                                              u16* __restrict__ out) {
  size_t i = ((size_t)blockIdx.x * 256 + threadIdx.x) * 4;
  float4 v = *(const float4*)(in + i);
  ushort4 b = { f2b(v.x), f2b(v.y), f2b(v.z), f2b(v.w) };
  *(ushort4*)(out + i) = b;
}

// --------------- small bias-vector precomputes (all zero in practice) --------
__global__ __launch_bounds__(256) void k_biasvec(const float* __restrict__ qw,
                                                 const float* __restrict__ kb,
                                                 const float* __restrict__ kw,
                                                 const float* __restrict__ qb,
                                                 float* __restrict__ qwkb,
                                                 float* __restrict__ kwqb,
                                                 float* __restrict__ kbqb) {
  int gw = (blockIdx.x * 256 + threadIdx.x) >> 6;
  int lane = threadIdx.x & 63;
  if (gw < 2048) {
    int t = gw >> 9, c = gw & 511;
    const float* row = qw + ((size_t)t * DIM + c) * DIM;
    const float* v = kb + (size_t)t * DIM;
    float s = 0;
#pragma unroll
    for (int j = 0; j < 8; j++) s += row[lane * 8 + j] * v[lane * 8 + j];
    s = wsum(s);
    if (lane == 0) qwkb[(size_t)t * DIM + c] = s;
  } else if (gw < 4096) {
    int t = (gw - 2048) >> 9, d = gw & 511;
    const float* row = kw + ((size_t)t * DIM + d) * DIM;
    const float* v = qb + (size_t)t * DIM;
    float s = 0;
#pragma unroll
    for (int j = 0; j < 8; j++) s += row[lane * 8 + j] * v[lane * 8 + j];
    s = wsum(s);
    if (lane == 0) kwqb[(size_t)t * DIM + d] = s;
  } else if (gw < 4100) {
    int t = gw - 4096;
    const float* a = kb + (size_t)t * DIM;
    const float* c = qb + (size_t)t * DIM;
    float s = 0;
#pragma unroll
    for (int j = 0; j < 8; j++) s += a[lane * 8 + j] * c[lane * 8 + j];
    s = wsum(s);
    if (lane == 0) kbqb[t] = s;
  }
}

// ---------------- 128x128 bf16 MFMA GEMM mainloop (NT: A MxK, B NxK) ---------
__device__ __forceinline__ void gemm128(const u16* __restrict__ Ag, int lda,
                                        const u16* __restrict__ Bg, int ldb,
                                        int K, f32x4 acc[4][4]) {
  __shared__ __align__(16) u16 lA[4096];
  __shared__ __align__(16) u16 lB[4096];
  const int tid = threadIdx.x;
  const int lane = tid & 63;
  const int wave = tid >> 6;
  const int wm = wave >> 1, wn = wave & 1;
  const u16* a0 = Ag + (size_t)(tid >> 2) * lda + (tid & 3) * 8;
  const u16* a1 = a0 + (size_t)64 * lda;
  const u16* b0 = Bg + (size_t)(tid >> 2) * ldb + (tid & 3) * 8;
  const u16* b1 = b0 + (size_t)64 * ldb;
  u16* la0 = &lA[tid * 8];
  u16* la1 = &lA[2048 + tid * 8];
  u16* lb0 = &lB[tid * 8];
  u16* lb1 = &lB[2048 + tid * 8];
  const int ao = (wm * 64 + (lane & 15)) * 32 + (lane >> 4) * 8;
  const int bo = (wn * 64 + (lane & 15)) * 32 + (lane >> 4) * 8;
  for (int k0 = 0; k0 < K; k0 += 32) {
    __syncthreads();
    GLOAD16(a0 + k0, la0);
    GLOAD16(a1 + k0, la1);
    GLOAD16(b0 + k0, lb0);
    GLOAD16(b1 + k0, lb1);
    __syncthreads();
    short8 af[4], bf[4];
#pragma unroll
    for (int i = 0; i < 4; i++) {
      af[i] = *(const short8*)&lA[ao + i * 512];
      bf[i] = *(const short8*)&lB[bo + i * 512];
    }
#pragma unroll
    for (int mi = 0; mi < 4; mi++)
#pragma unroll
      for (int ni = 0; ni < 4; ni++)
        acc[mi][ni] = __builtin_amdgcn_mfma_f32_16x16x32_bf16(af[mi], bf[ni],
                                                              acc[mi][ni], 0, 0, 0);
  }
}

// ---------------- expert up-GEMM: h = gelu(x@W1 + b1), bf16 out --------------
__global__ __launch_bounds__(256) void k_gemm_up(const u16* __restrict__ xsb,
                                                 const u16* __restrict__ tib,
                                                 const u16* __restrict__ w1t,
                                                 const float* __restrict__ sb1,
                                                 const float* __restrict__ tb1,
                                                 u16* __restrict__ hbuf,
                                                 int expertBase) {
  int gz = blockIdx.z, ge = expertBase + gz;
  const u16* A;
  const float* bias;
  if (ge < 4) { A = xsb; bias = sb1 + (size_t)ge * HDIM; }
  else {
    int te = ge - 4;
    A = tib + (size_t)(te >> 2) * BD;
    bias = tb1 + (size_t)te * HDIM;
  }
  const u16* W = w1t + (size_t)ge * ((size_t)HDIM * DIM);
  int m0 = blockIdx.y * 128, n0 = blockIdx.x * 128;
  f32x4 acc[4][4] = {};
  gemm128(A + (size_t)m0 * DIM, DIM, W + (size_t)n0 * DIM, DIM, DIM, acc);
  u16* out = hbuf + (size_t)gz * BH;
  const int lane = threadIdx.x & 63, wave = threadIdx.x >> 6;
  const int rbase = m0 + (wave >> 1) * 64 + (lane >> 4) * 4;
  const int cbase = n0 + (wave & 1) * 64 + (lane & 15);
#pragma unroll
  for (int mi = 0; mi < 4; mi++)
#pragma unroll
    for (int ni = 0; ni < 4; ni++)
#pragma unroll
      for (int r = 0; r < 4; r++) {
        int row = rbase + mi * 16 + r;
        int col = cbase + ni * 16;
        float v = acc[mi][ni][r] + bias[col];
        out[(size_t)row * HDIM + col] = f2b(fgelu(v));
      }
}

// ---- fused down-GEMM + bias + residual + LayerNorm -> stacked (post-LN) -----
// tile: 64 rows x 512 cols (full D), K=HDIM. 8 waves: wm=wave>>2 (2), wn=wave&3 (4).
// swapped-operand MFMA: lane value = C[row = lane&15 (+16*mf+32*wm)]
//                                     [col = (lane>>4)*4+r (+16*nf+128*wn)]
__global__ __launch_bounds__(512) void k_down_ln(const u16* __restrict__ hbuf,
                                                 const u16* __restrict__ w2t,
                                                 const float* __restrict__ sb2,
                                                 const float* __restrict__ tb2,
                                                 const float* __restrict__ xsf,
                                                 const float* __restrict__ ti,
                                                 const float* __restrict__ sg,
                                                 const float* __restrict__ sbt,
                                                 const float* __restrict__ tg,
                                                 const float* __restrict__ tbt,
                                                 float* __restrict__ stacked,
                                                 int expertBase) {
  __shared__ __align__(16) u16 lA[2048];    // 64 x 32 bf16
  __shared__ __align__(16) u16 lB[16384];   // 512 x 32 bf16
  int gz = blockIdx.z, ge = expertBase + gz;
  const int tid = threadIdx.x;
  const int lane = tid & 63, wave = tid >> 6;
  const int wm = wave >> 2, wn = wave & 3;
  const int rl = lane & 15, c4 = (lane >> 4) * 4;
  const int m0 = blockIdx.x * 64;
  const u16* Ag = hbuf + (size_t)gz * BH + (size_t)m0 * HDIM;
  const u16* Bg = w2t + (size_t)ge * ((size_t)DIM * HDIM);
  const u16* aS = Ag + (size_t)(tid >> 2) * HDIM + (tid & 3) * 8;
  u16* aD = &lA[tid * 8];
  const u16* bS = Bg + (size_t)(tid >> 2) * HDIM + (tid & 3) * 8;
  f32x4 acc[2][8] = {};
  for (int k0 = 0; k0 < HDIM; k0 += 32) {
    __syncthreads();
    if (tid < 256) GLOAD16(aS + k0, aD);
#pragma unroll
    for (int j = 0; j < 4; j++)
      GLOAD16(bS + (size_t)j * 128 * HDIM + k0, &lB[((size_t)tid + j * 512) * 8]);
    __syncthreads();
    short8 af[2], bf[8];
#pragma unroll
    for (int mf = 0; mf < 2; mf++)
      af[mf] = *(const short8*)&lA[(wm * 32 + mf * 16 + rl) * 32 + (lane >> 4) * 8];
#pragma unroll
    for (int nf = 0; nf < 8; nf++)
      bf[nf] = *(const short8*)&lB[(wn * 128 + nf * 16 + rl) * 32 + (lane >> 4) * 8];
#pragma unroll
    for (int mf = 0; mf < 2; mf++)
#pragma unroll
      for (int nf = 0; nf < 8; nf++)
        acc[mf][nf] = __builtin_amdgcn_mfma_f32_16x16x32_bf16(bf[nf], af[mf],
                                                              acc[mf][nf], 0, 0, 0);
  }
  // ---- epilogue: bias + residual, then row LN over all 512 cols ----
  const float* bias; const float* res; const float* gp; const float* bp;
  int te = ge - 4;
  if (ge < 4) {
    bias = sb2 + (size_t)ge * DIM; res = xsf;
    gp = sg + (size_t)ge * DIM;    bp = sbt + (size_t)ge * DIM;
  } else {
    bias = tb2 + (size_t)te * DIM; res = ti + (size_t)(te >> 2) * BD;
    gp = tg + (size_t)te * DIM;    bp = tbt + (size_t)te * DIM;
  }
  float sv[2], qv[2];
#pragma unroll
  for (int mf = 0; mf < 2; mf++) {
    int row = m0 + wm * 32 + mf * 16 + rl;
    float s = 0, q = 0;
#pragma unroll
    for (int nf = 0; nf < 8; nf++) {
      int n = wn * 128 + nf * 16 + c4;
      float4 bb = *(const float4*)(bias + n);
      float4 rr = *(const float4*)(res + (size_t)row * DIM + n);
#pragma unroll
      for (int r = 0; r < 4; r++) {
        float v = acc[mf][nf][r] + ((const float*)&bb)[r] + ((const float*)&rr)[r];
        acc[mf][nf][r] = v; s += v; q += v * v;
      }
    }
    s += __shfl_xor(s, 16); s += __shfl_xor(s, 32);
    q += __shfl_xor(q, 16); q += __shfl_xor(q, 32);
    sv[mf] = s; qv[mf] = q;
  }
  float* partS = (float*)lA;        // [4 wn][64 rows]
  float* partQ = partS + 256;
  __syncthreads();                  // main-loop LDS use finished on all waves
  if (lane < 16) {
#pragma unroll
    for (int mf = 0; mf < 2; mf++) {
      partS[wn * 64 + wm * 32 + mf * 16 + lane] = sv[mf];
      partQ[wn * 64 + wm * 32 + mf * 16 + lane] = qv[mf];
    }
  }
  __syncthreads();
  float mu[2], rsg[2];
#pragma unroll
  for (int mf = 0; mf < 2; mf++) {
    int ridx = wm * 32 + mf * 16 + rl;
    float S = partS[ridx] + partS[64 + ridx] + partS[128 + ridx] + partS[192 + ridx];
    float Q = partQ[ridx] + partQ[64 + ridx] + partQ[128 + ridx] + partQ[192 + ridx];
    float m = S * (1.0f / DIM);
    float var = Q * (1.0f / DIM) - m * m;
    mu[mf] = m; rsg[mf] = rsqrtf(var + 1e-5f);
  }
#pragma unroll
  for (int nf = 0; nf < 8; nf++) {
    int n = wn * 128 + nf * 16 + c4;
    float4 gg = *(const float4*)(gp + n);
    float4 bb = *(const float4*)(bp + n);
#pragma unroll
    for (int mf = 0; mf < 2; mf++) {
      int row = m0 + wm * 32 + mf * 16 + rl;
      float4 y;
#pragma unroll
      for (int r = 0; r < 4; r++)
        ((float*)&y)[r] = (acc[mf][nf][r] - mu[mf]) * rsg[mf] *
                          ((const float*)&gg)[r] + ((const float*)&bb)[r];
      if (ge < 4) {
#pragma unroll
        for (int t = 0; t < 4; t++)
          *(float4*)(stacked + (((size_t)t * 8 + ge) * BB + row) * DIM + n) = y;
      } else {
        *(float4*)(stacked + (((size_t)(te >> 2) * 8 + 4 + (te & 3)) * BB + row) * DIM + n) = y;
      }
    }
  }
}

// ---------------- MT[t] = kw[t] @ qw[t]^T  (bf16 out) ------------------------
__global__ __launch_bounds__(256) void k_gemm_mt(const u16* __restrict__ kwb,
                                                 const u16* __restrict__ qwb,
                                                 u16* __restrict__ mt) {
  int t = blockIdx.z;
  int m0 = blockIdx.y * 128, n0 = blockIdx.x * 128;
  f32x4 acc[4][4] = {};
  gemm128(kwb + (size_t)t * D2 + (size_t)m0 * DIM, DIM,
          qwb + (size_t)t * D2 + (size_t)n0 * DIM, DIM, DIM, acc);
  const int lane = threadIdx.x & 63, wave = threadIdx.x >> 6;
  const int rbase = m0 + (wave >> 1) * 64 + (lane >> 4) * 4;
  const int cbase = n0 + (wave & 1) * 64 + (lane & 15);
#pragma unroll
  for (int mi = 0; mi < 4; mi++)
#pragma unroll
    for (int ni = 0; ni < 4; ni++)
#pragma unroll
      for (int r = 0; r < 4; r++)
        mt[(size_t)t * D2 + (size_t)(rbase + mi * 16 + r) * DIM + cbase + ni * 16] =
            f2b(acc[mi][ni][r]);
}

// ---------------- qk[t] = x[t] @ MT[t]^T + kwqb[t]  (f32 out) ----------------
__global__ __launch_bounds__(256) void k_gemm_qk(const u16* __restrict__ tib,
                                                 const u16* __restrict__ mt,
                                                 const float* __restrict__ kwqb,
                                                 float* __restrict__ qk) {
  int t = blockIdx.z;
  int m0 = blockIdx.y * 128, n0 = blockIdx.x * 128;
  f32x4 acc[4][4] = {};
  gemm128(tib + (size_t)t * BD + (size_t)m0 * DIM, DIM,
          mt + (size_t)t * D2 + (size_t)n0 * DIM, DIM, DIM, acc);
  const int lane = threadIdx.x & 63, wave = threadIdx.x >> 6;
  const int rbase = m0 + (wave >> 1) * 64 + (lane >> 4) * 4;
  const int cbase = n0 + (wave & 1) * 64 + (lane & 15);
#pragma unroll
  for (int mi = 0; mi < 4; mi++)
#pragma unroll
    for (int ni = 0; ni < 4; ni++)
#pragma unroll
      for (int r = 0; r < 4; r++) {
        int col = cbase + ni * 16;
        qk[(size_t)t * BD + (size_t)(rbase + mi * 16 + r) * DIM + col] =
            acc[mi][ni][r] + kwqb[(size_t)t * DIM + col];
      }
}

// ------------ fused scores + softmax + gating (one wave per (t,b)) -----------
__global__ __launch_bounds__(256) void k_score(const float* __restrict__ stk,
                                               const float* __restrict__ qk,
                                               const float* __restrict__ xin,
                                               const float* __restrict__ qwkb,
                                               const float* __restrict__ kbqb,
                                               float* __restrict__ gated,
                                               float* __restrict__ wout) {
  int gw = (blockIdx.x * 256 + threadIdx.x) >> 6;
  int lane = threadIdx.x & 63;
  int b = gw & (BB - 1), t = gw >> 12;
  int d0 = lane * 8;
  size_t rowoff = ((size_t)t * BB + b) * DIM + d0;
  float qr[8], xr[8], wk[8];
  *(float4*)&qr[0] = *(const float4*)(qk + rowoff);
  *(float4*)&qr[4] = *(const float4*)(qk + rowoff + 4);
  *(float4*)&xr[0] = *(const float4*)(xin + rowoff);
  *(float4*)&xr[4] = *(const float4*)(xin + rowoff + 4);
  *(float4*)&wk[0] = *(const float4*)(qwkb + (size_t)t * DIM + d0);
  *(float4*)&wk[4] = *(const float4*)(qwkb + (size_t)t * DIM + d0 + 4);
  float stv[8][8];
  float dots[8];
#pragma unroll
  for (int n = 0; n < 8; n++) {
    const float* sr = stk + (((size_t)t * 8 + n) * BB + b) * DIM + d0;
    *(float4*)&stv[n][0] = *(const float4*)(sr);
    *(float4*)&stv[n][4] = *(const float4*)(sr + 4);
    float s = 0;
#pragma unroll
    for (int j = 0; j < 8; j++) s += stv[n][j] * qr[j];
    dots[n] = wsum(s);
  }
  float sbp = 0;
#pragma unroll
  for (int j = 0; j < 8; j++) sbp += xr[j] * wk[j];
  float sb = wsum(sbp) + kbqb[t];
  const float inv = 0.04419417382415922f;  // 1/sqrt(512)
  float sc[8], e[8];
  float mx = -1e30f;
#pragma unroll
  for (int n = 0; n < 8; n++) { sc[n] = (dots[n] + sb) * inv; mx = fmaxf(mx, sc[n]); }
  float den = 0;
#pragma unroll
  for (int n = 0; n < 8; n++) { e[n] = expf(sc[n] - mx); den += e[n]; }
  float rden = 1.0f / den;
  float wv[8];
#pragma unroll
  for (int n = 0; n < 8; n++) wv[n] = e[n] * rden;
  float wsel = 0;
#pragma unroll
  for (int n = 0; n < 8; n++) wsel = (lane == n) ? wv[n] : wsel;
  if (lane < 8) wout[((size_t)t * BB + b) * 8 + lane] = wsel;
  float g[8];
#pragma unroll
  for (int j = 0; j < 8; j++) {
    float s = 0;
#pragma unroll
    for (int n = 0; n < 8; n++) s += wv[n] * stv[n][j];
    g[j] = s;
  }
  float* go = gated + rowoff;
  *(float4*)(go) = *(float4*)&g[0];
  *(float4*)(go + 4) = *(float4*)&g[4];
}

// ============================ host launcher ==================================
extern "C" void kernel_launch(void* const* d_in, const int* in_sizes, int n_in,
                              void* d_out, int out_size, void* d_ws, size_t ws_size,
                              hipStream_t stream) {
  const float* ti  = (const float*)d_in[0];
  const float* sw1 = (const float*)d_in[1];
  const float* sb1 = (const float*)d_in[2];
  const float* sw2 = (const float*)d_in[3];
  const float* sb2 = (const float*)d_in[4];
  const float* sg  = (const float*)d_in[5];
  const float* sbt = (const float*)d_in[6];
  const float* tw1 = (const float*)d_in[7];
  const float* tb1 = (const float*)d_in[8];
  const float* tw2 = (const float*)d_in[9];
  const float* tb2 = (const float*)d_in[10];
  const float* tg  = (const float*)d_in[11];
  const float* tbt = (const float*)d_in[12];
  const float* qw  = (const float*)d_in[13];
  const float* qb  = (const float*)d_in[14];
  const float* kw  = (const float*)d_in[15];
  const float* kb  = (const float*)d_in[16];

  float* out = (float*)d_out;
  float* gated   = out;                                   // T*B*D
  float* weights = out + (size_t)TT * BB * DIM;           // T*B*8
  float* stacked = weights + (size_t)TT * BB * 8;         // T*8*B*D

  char* ws = (char*)d_ws;
  u16*   tib  = (u16*)(ws);                     // 16,777,216 B
  u16*   xsb  = (u16*)(ws + 16777216);          //  4,194,304 B
  float* xsf  = (float*)(ws + 20971520);        //  8,388,608 B
  u16*   w1t  = (u16*)(ws + 29360128);          // 20,971,520 B
  u16*   w2t  = (u16*)(ws + 50331648);          // 20,971,520 B
  u16*   qwb  = (u16*)(ws + 71303168);          //  2,097,152 B
  u16*   kwb  = (u16*)(ws + 73400320);          //  2,097,152 B
  u16*   mt   = (u16*)(ws + 75497472);          //  2,097,152 B
  float* qk   = (float*)(ws + 77594624);        // 33,554,432 B
  float* qwkb = (float*)(ws + 111149056);       //      8,192 B
  float* kwqb = (float*)(ws + 111157248);       //      8,192 B
  float* kbqb = (float*)(ws + 111165440);       //        256 B
  u16*   hbuf = (u16*)(ws + 111165696);         // chunk * 8,388,608 B

  const size_t hbase = 111165696;
  int chunk = 20;
  if (ws_size < hbase + (size_t)20 * BH * 2)
    chunk = (ws_size >= hbase + (size_t)4 * BH * 2) ? 4 : 1;

  k_prep<<<2048, 256, 0, stream>>>(ti, tib, xsb, xsf);

  k_tcast<<<dim3(32, 16, 4), 256, 0, stream>>>(sw1, w1t, DIM, HDIM);
  k_tcast<<<dim3(32, 16, 16), 256, 0, stream>>>(tw1, w1t + (size_t)4 * HDIM * DIM, DIM, HDIM);
  k_tcast<<<dim3(16, 32, 4), 256, 0, stream>>>(sw2, w2t, HDIM, DIM);
  k_tcast<<<dim3(16, 32, 16), 256, 0, stream>>>(tw2, w2t + (size_t)4 * DIM * HDIM, HDIM, DIM);
  k_cast<<<1024, 256, 0, stream>>>(qw, qwb);
  k_cast<<<1024, 256, 0, stream>>>(kw, kwb);
  k_biasvec<<<1025, 256, 0, stream>>>(qw, kb, kw, qb, qwkb, kwqb, kbqb);

  k_gemm_mt<<<dim3(4, 4, 4), 256, 0, stream>>>(kwb, qwb, mt);

  for (int base = 0; base < NEXP; base += chunk) {
    int c = NEXP - base < chunk ? NEXP - base : chunk;
    k_gemm_up<<<dim3(8, 32, c), 256, 0, stream>>>(xsb, tib, w1t, sb1, tb1, hbuf, base);
    k_down_ln<<<dim3(64, 1, c), 512, 0, stream>>>(hbuf, w2t, sb2, tb2, xsf, ti,
                                                  sg, sbt, tg, tbt, stacked, base);
  }

  k_gemm_qk<<<dim3(4, 32, 4), 256, 0, stream>>>(tib, mt, kwqb, qk);

  k_score<<<4096, 256, 0, stream>>>(stacked, qk, ti, qwkb, kbqb, gated, weights);
}